// Round 2
// baseline (893.496 us; speedup 1.0000x reference)
//
#include <hip/hip_runtime.h>
#include <math.h>

#define B_ 1024
#define N_ 64
#define F_ 512

typedef const __attribute__((address_space(1))) float* gptr_t;
typedef __attribute__((address_space(3))) float* lptr_t;

__device__ __forceinline__ void gload16(const float* g, float* l) {
  __builtin_amdgcn_global_load_lds((gptr_t)g, (lptr_t)l, 16, 0, 0);
}

#define COMP(v, kk) ((kk) == 0 ? (v).x : (kk) == 1 ? (v).y : (kk) == 2 ? (v).z : (v).w)

// ---------------------------------------------------------------------------
// Kernel 1: Wh = h @ W as one fused GEMM, M=65536 (B*N), K=512, N=512.
// 128x128 tile per block, 256 threads, 8x8 micro-tile, Kc=32 double-buffered
// LDS via global_load_lds(16B). A stored with XOR-swizzled f4 columns
// (pre-swizzled GLOBAL source, linear LDS dest) -> conflict-free A reads.
// ---------------------------------------------------------------------------
__global__ __launch_bounds__(256, 2) void k_wh(const float* __restrict__ hA,
                                               const float* __restrict__ W,
                                               float* __restrict__ Wh) {
  __shared__ float As[2][128 * 32];
  __shared__ float Bs[2][32 * 128];

  const int bid = blockIdx.x;                    // 0..2047
  const int wg  = (bid & 7) * 256 + (bid >> 3);  // XCD-grouped logical id
  const int mt  = wg >> 2;                       // M-tile 0..511
  const int nt  = wg & 3;                        // N-tile 0..3
  const int t    = threadIdx.x;
  const int tm   = t >> 4;                       // rows tm*8..+7
  const int tn   = t & 15;                       // cols tn*8..+7
  const int w    = t >> 6;                       // wave id
  const int lane = t & 63;

  const float* Ab = hA + (size_t)mt * 128 * F_;
  const float* Bb = W + nt * 128;

  // Per-thread staging descriptors (4 wave-chunks of 1KB each for A and B).
  int Aoff[4], Boff[4], ldsOff[4];
#pragma unroll
  for (int i = 0; i < 4; ++i) {
    int c = w + 4 * i;             // wave-uniform chunk id
    int e = c * 64 + lane;         // f4 slot in 128x8 tile
    int row = e >> 3;
    int j = e & 7;
    int jg = j ^ ((row >> 3) & 3); // inverse-swizzled global column
    Aoff[i] = row * F_ + jg * 4;
    int k = e >> 5;                // B: 32 f4 per k-row
    int n4 = e & 31;
    Boff[i] = k * F_ + n4 * 4;
    ldsOff[i] = c * 256;           // floats
  }

  float acc[8][8];
#pragma unroll
  for (int i = 0; i < 8; ++i)
#pragma unroll
    for (int c = 0; c < 8; ++c) acc[i][c] = 0.f;

#define STAGE(buf, k0)                                                  \
  do {                                                                  \
    _Pragma("unroll") for (int i_ = 0; i_ < 4; ++i_)                    \
        gload16(Ab + (size_t)(k0) + Aoff[i_], &As[buf][ldsOff[i_]]);    \
    _Pragma("unroll") for (int i_ = 0; i_ < 4; ++i_)                    \
        gload16(Bb + (size_t)(k0) * F_ + Boff[i_], &Bs[buf][ldsOff[i_]]); \
  } while (0)

#define COMPUTE(buf)                                                    \
  do {                                                                  \
    const float4* Av = (const float4*)As[buf];                          \
    const float4* Bv = (const float4*)Bs[buf];                          \
    _Pragma("unroll") for (int k4 = 0; k4 < 8; ++k4) {                  \
      float4 a[8];                                                      \
      _Pragma("unroll") for (int i_ = 0; i_ < 8; ++i_)                  \
          a[i_] = Av[(tm * 8 + i_) * 8 + (k4 ^ (tm & 3))];              \
      _Pragma("unroll") for (int kk = 0; kk < 4; ++kk) {                \
        float4 bl = Bv[(k4 * 4 + kk) * 32 + tn * 2];                    \
        float4 bh = Bv[(k4 * 4 + kk) * 32 + tn * 2 + 1];                \
        float bb[8] = {bl.x, bl.y, bl.z, bl.w, bh.x, bh.y, bh.z, bh.w}; \
        _Pragma("unroll") for (int i_ = 0; i_ < 8; ++i_) {              \
          float av = COMP(a[i_], kk);                                   \
          _Pragma("unroll") for (int c_ = 0; c_ < 8; ++c_)              \
              acc[i_][c_] += av * bb[c_];                               \
        }                                                               \
      }                                                                 \
    }                                                                   \
  } while (0)

  STAGE(0, 0);
  __syncthreads();
#pragma unroll 1
  for (int kt = 0; kt < 16; ++kt) {
    int cur = kt & 1;
    if (kt < 15) STAGE(cur ^ 1, (kt + 1) * 32);
    COMPUTE(cur);
    __syncthreads();
  }

  float* whb = Wh + (size_t)mt * 128 * F_ + nt * 128;
#pragma unroll
  for (int i = 0; i < 8; ++i) {
    float4 v0 = make_float4(acc[i][0], acc[i][1], acc[i][2], acc[i][3]);
    float4 v1 = make_float4(acc[i][4], acc[i][5], acc[i][6], acc[i][7]);
    *(float4*)(whb + (tm * 8 + i) * F_ + tn * 8) = v0;
    *(float4*)(whb + (tm * 8 + i) * F_ + tn * 8 + 4) = v1;
  }
#undef STAGE
#undef COMPUTE
}

// ---------------------------------------------------------------------------
// Kernel 2: per-batch pipeline (unchanged from round 1). Grid = B blocks.
// ---------------------------------------------------------------------------
__global__ __launch_bounds__(256) void k_attn(const float* __restrict__ Wh,
                                              const float* __restrict__ A1,
                                              const float* __restrict__ A2,
                                              const float* __restrict__ betap,
                                              float* __restrict__ out) {
  __shared__ float sm[12736];
  float* e_s   = sm;
  float* hid_s = sm + 4160;
  float* xm_s  = sm + 4160;
  float* a_s   = sm + 8512;
  float* wh_s  = sm + 4160;
  float* mu    = sm + 12608;
  float* nrm   = sm + 12672;

  const int b = blockIdx.x;
  const int t = threadIdx.x;
  const float beta = betap[0];
  const float* whb = Wh + (size_t)b * N_ * F_;

  // ---- row means of Wh[b] ----
  {
    int n = t >> 2, q = t & 3;
    const float* row = whb + n * F_ + q * 128;
    float s = 0.f;
#pragma unroll
    for (int i = 0; i < 32; ++i) {
      float4 v = *(const float4*)(row + i * 4);
      s += v.x + v.y + v.z + v.w;
    }
    s += __shfl_xor(s, 1);
    s += __shfl_xor(s, 2);
    if (q == 0) mu[n] = s * (1.f / F_);
  }
  __syncthreads();

  // ---- cov: thread owns pairs (n = tn+16r, m = tm+16c), 4x4 ----
  const int tm = t & 15, tn = t >> 4;
  float cov[4][4];
#pragma unroll
  for (int r = 0; r < 4; ++r)
#pragma unroll
    for (int c = 0; c < 4; ++c) cov[r][c] = 0.f;

  for (int ch = 0; ch < 8; ++ch) {
#pragma unroll
    for (int i = 0; i < 4; ++i) {
      int id = t + 256 * i;
      int r = id >> 4, c4 = id & 15;
      float4 v = *(const float4*)(whb + r * F_ + ch * 64 + c4 * 4);
      float m_ = mu[r];
      v.x -= m_; v.y -= m_; v.z -= m_; v.w -= m_;
      *(float4*)(&xm_s[r * 68 + c4 * 4]) = v;
    }
    __syncthreads();
#pragma unroll
    for (int f0 = 0; f0 < 64; f0 += 4) {
      float4 xa[4], xb[4];
#pragma unroll
      for (int r = 0; r < 4; ++r) xa[r] = *(const float4*)(&xm_s[(tn + 16 * r) * 68 + f0]);
#pragma unroll
      for (int c = 0; c < 4; ++c) xb[c] = *(const float4*)(&xm_s[(tm + 16 * c) * 68 + f0]);
#pragma unroll
      for (int r = 0; r < 4; ++r)
#pragma unroll
        for (int c = 0; c < 4; ++c)
          cov[r][c] += xa[r].x * xb[c].x + xa[r].y * xb[c].y +
                       xa[r].z * xb[c].z + xa[r].w * xb[c].w;
    }
    __syncthreads();
  }

  if (tn == tm) {
#pragma unroll
    for (int r = 0; r < 4; ++r) nrm[tn + 16 * r] = sqrtf(cov[r][r]);
  }
  __syncthreads();

#pragma unroll
  for (int r = 0; r < 4; ++r) {
    int n = tn + 16 * r;
#pragma unroll
    for (int c = 0; c < 4; ++c) {
      int m = tm + 16 * c;
      float denom = nrm[n] * nrm[m] + 1e-8f;
      e_s[n * 65 + m] = beta * fabsf(cov[r][c] / denom);
    }
  }
  __syncthreads();

  // ---- MLP ----
  float adjp[4][4];
#pragma unroll
  for (int r = 0; r < 4; ++r)
#pragma unroll
    for (int c = 0; c < 4; ++c) adjp[r][c] = 0.f;

  const int rg = t >> 4;
  const int jg = t & 15;

  for (int kc = 0; kc < 4; ++kc) {
#pragma unroll
    for (int i = 0; i < 4; ++i) {
      int id = t + 256 * i;
      int m = id >> 4, c4 = id & 15;
      *(float4*)(&a_s[m * 64 + c4 * 4]) =
          *(const float4*)(A1 + (size_t)m * 256 + kc * 64 + c4 * 4);
    }
    __syncthreads();

    float h1[4][4];
#pragma unroll
    for (int rr = 0; rr < 4; ++rr)
#pragma unroll
      for (int jj = 0; jj < 4; ++jj) h1[rr][jj] = 0.f;
    for (int m = 0; m < 64; ++m) {
      float er[4];
#pragma unroll
      for (int rr = 0; rr < 4; ++rr) er[rr] = e_s[(rg * 4 + rr) * 65 + m];
      float4 a4 = *(const float4*)(&a_s[m * 64 + jg * 4]);
#pragma unroll
      for (int rr = 0; rr < 4; ++rr) {
        h1[rr][0] += er[rr] * a4.x;
        h1[rr][1] += er[rr] * a4.y;
        h1[rr][2] += er[rr] * a4.z;
        h1[rr][3] += er[rr] * a4.w;
      }
    }
#pragma unroll
    for (int rr = 0; rr < 4; ++rr) {
      float4 v = make_float4(fmaxf(h1[rr][0], 0.f), fmaxf(h1[rr][1], 0.f),
                             fmaxf(h1[rr][2], 0.f), fmaxf(h1[rr][3], 0.f));
      *(float4*)(&hid_s[(rg * 4 + rr) * 64 + jg * 4]) = v;
    }
    __syncthreads();

#pragma unroll
    for (int i = 0; i < 4; ++i) {
      int id = t + 256 * i;
      int j = id >> 4, c4 = id & 15;
      *(float4*)(&a_s[j * 64 + c4 * 4]) =
          *(const float4*)(A2 + (size_t)(kc * 64 + j) * 64 + c4 * 4);
    }
    __syncthreads();

#pragma unroll
    for (int j0 = 0; j0 < 64; j0 += 4) {
      float4 hr[4], a2v[4];
#pragma unroll
      for (int r = 0; r < 4; ++r) hr[r] = *(const float4*)(&hid_s[(tn * 4 + r) * 64 + j0]);
#pragma unroll
      for (int jj = 0; jj < 4; ++jj) a2v[jj] = *(const float4*)(&a_s[(j0 + jj) * 64 + tm * 4]);
#pragma unroll
      for (int r = 0; r < 4; ++r) {
        float hv[4] = {hr[r].x, hr[r].y, hr[r].z, hr[r].w};
#pragma unroll
        for (int jj = 0; jj < 4; ++jj) {
          adjp[r][0] += hv[jj] * a2v[jj].x;
          adjp[r][1] += hv[jj] * a2v[jj].y;
          adjp[r][2] += hv[jj] * a2v[jj].z;
          adjp[r][3] += hv[jj] * a2v[jj].w;
        }
      }
    }
    __syncthreads();
  }

  // mask
#pragma unroll
  for (int r = 0; r < 4; ++r) {
    int n = tn * 4 + r;
#pragma unroll
    for (int c = 0; c < 4; ++c) {
      int m = tm * 4 + c;
      float ev = e_s[n * 65 + m];
      float pre = ev + adjp[r][c];
      e_s[n * 65 + m] = (pre > 0.f) ? ev : -1e12f;
    }
  }
  __syncthreads();

  // softmax
  {
    int n = t >> 2, p = t & 3;
    float mx = -3.0e38f;
#pragma unroll
    for (int i = 0; i < 16; ++i) mx = fmaxf(mx, e_s[n * 65 + p * 16 + i]);
    mx = fmaxf(mx, __shfl_xor(mx, 1));
    mx = fmaxf(mx, __shfl_xor(mx, 2));
    float ev[16];
    float ssum = 0.f;
#pragma unroll
    for (int i = 0; i < 16; ++i) {
      ev[i] = expf(e_s[n * 65 + p * 16 + i] - mx);
      ssum += ev[i];
    }
    ssum += __shfl_xor(ssum, 1);
    ssum += __shfl_xor(ssum, 2);
    float inv = 1.f / ssum;
#pragma unroll
    for (int i = 0; i < 16; ++i) e_s[n * 65 + p * 16 + i] = ev[i] * inv;
  }
  __syncthreads();

  // h' = attention @ Wh
  const int jf  = t & 31;
  const int rg2 = t >> 5;
  for (int ch = 0; ch < 4; ++ch) {
#pragma unroll
    for (int i = 0; i < 8; ++i) {
      int id = t + 256 * i;
      int r = id >> 5, c4 = id & 31;
      *(float4*)(&wh_s[r * 128 + c4 * 4]) =
          *(const float4*)(whb + r * F_ + ch * 128 + c4 * 4);
    }
    __syncthreads();
    float4 acc2[8];
#pragma unroll
    for (int rr = 0; rr < 8; ++rr) acc2[rr] = make_float4(0.f, 0.f, 0.f, 0.f);
    for (int m = 0; m < 64; ++m) {
      float4 wv = *(const float4*)(&wh_s[m * 128 + jf * 4]);
#pragma unroll
      for (int rr = 0; rr < 8; ++rr) {
        float a = e_s[(rg2 * 8 + rr) * 65 + m];
        acc2[rr].x += a * wv.x;
        acc2[rr].y += a * wv.y;
        acc2[rr].z += a * wv.z;
        acc2[rr].w += a * wv.w;
      }
    }
    float* ob = out + (size_t)b * N_ * F_ + ch * 128;
#pragma unroll
    for (int rr = 0; rr < 8; ++rr)
      *(float4*)(ob + (rg2 * 8 + rr) * F_ + jf * 4) = acc2[rr];
    __syncthreads();
  }
}

extern "C" void kernel_launch(void* const* d_in, const int* in_sizes, int n_in,
                              void* d_out, int out_size, void* d_ws, size_t ws_size,
                              hipStream_t stream) {
  const float* h    = (const float*)d_in[0];
  const float* W    = (const float*)d_in[1];
  const float* beta = (const float*)d_in[2];
  const float* A1   = (const float*)d_in[3];
  const float* A2   = (const float*)d_in[4];
  float* out = (float*)d_out;
  float* Wh  = (float*)d_ws;  // B*N*F*4 = 128 MiB workspace

  k_wh<<<2048, 256, 0, stream>>>(h, W, Wh);
  k_attn<<<B_, 256, 0, stream>>>(Wh, A1, A2, beta, out);
}